// Round 4
// baseline (581.133 us; speedup 1.0000x reference)
//
#include <hip/hip_runtime.h>
#include <cstdint>
#include <cstddef>

#define N_NODES 50000
#define N_EDGES 800000
#define DIM 64
#define NREL 8
#define NBLK 782                 // ceil(N_NODES/64)
#define NPAD (NBLK * 64)         // 50048
#define NBUCK 196                // ceil(N_NODES/256)

typedef unsigned short u16;
typedef unsigned int u32;
typedef float f32x4 __attribute__((ext_vector_type(4)));
typedef short bf16x8 __attribute__((ext_vector_type(8)));

__device__ __forceinline__ u16 f2b(float f) {
  union { float f; u32 u; } c; c.f = f;
  u32 u = c.u;
  return (u16)((u + 0x7fffu + ((u >> 16) & 1u)) >> 16);  // RNE
}
__device__ __forceinline__ float b2f(u16 v) {
  union { u32 u; float f; } c; c.u = ((u32)v) << 16;
  return c.f;
}

// ---- casts -----------------------------------------------------------------
__global__ void k_cast_h(const float* __restrict__ h, u16* __restrict__ hb) {
  size_t i4 = (size_t)blockIdx.x * 256 + threadIdx.x;
  size_t base = i4 * 4;
  if (base >= (size_t)NPAD * DIM) return;
  size_t row = base >> 6;
  u16 o[4];
  if (row < N_NODES) {
    float4 v = *(const float4*)(h + base);
    o[0] = f2b(v.x); o[1] = f2b(v.y); o[2] = f2b(v.z); o[3] = f2b(v.w);
  } else {
    o[0] = o[1] = o[2] = o[3] = 0;
  }
  uint2 s; s.x = (u32)o[0] | ((u32)o[1] << 16); s.y = (u32)o[2] | ((u32)o[3] << 16);
  *(uint2*)(hb + base) = s;
}

// block r: WbT[r][d][k] = W[r][k][d] (bf16) ; Wa2[r,d] = sum_e W[r,d,e]*a[r,D+e]
__global__ void k_cast_wt(const float* __restrict__ W, const float* __restrict__ a,
                          u16* __restrict__ WbT, float* __restrict__ Wa2) {
  int r = blockIdx.x;
  for (int idx = threadIdx.x; idx < DIM * DIM; idx += 256) {
    int d = idx >> 6, k = idx & 63;
    WbT[((size_t)r * DIM + d) * DIM + k] = f2b(W[((size_t)r * DIM + k) * DIM + d]);
  }
  if (threadIdx.x < DIM) {
    int d = threadIdx.x;
    const float* Wr = W + (size_t)r * DIM * DIM + (size_t)d * DIM;
    const float* ar = a + (size_t)r * 2 * DIM + DIM;
    float acc = 0.f;
    #pragma unroll
    for (int e = 0; e < DIM; ++e) acc += Wr[e] * ar[e];
    Wa2[r * DIM + d] = acc;
  }
}

// Tb[16][64] bf16: rows 0..7 = a[r,:D] (dst side), rows 8..15 = Wa2[r] (src side)
__global__ void k_prep_tbl(const float* __restrict__ a, const float* __restrict__ Wa2,
                           u16* __restrict__ Tb) {
  int idx = threadIdx.x * 4;
  int row = idx >> 6;
  int k = idx & 63;
  #pragma unroll
  for (int j = 0; j < 4; ++j) {
    float v = (row < 8) ? a[row * 2 * DIM + k + j] : Wa2[(row - 8) * DIM + k + j];
    Tb[row * DIM + k + j] = f2b(v);
  }
}

// ---- bucketed CSR build ----------------------------------------------------
// bucket of node n = n>>8 (196 buckets of <=256 nodes)
__global__ void k_bhist(const int* __restrict__ dst, int* __restrict__ bcnt) {
  __shared__ int cnt[256];
  int t = threadIdx.x;
  cnt[t] = 0;
  __syncthreads();
  int i = blockIdx.x * 256 + t;
  if (i < N_EDGES / 4) {
    int4 d4 = ((const int4*)dst)[i];
    atomicAdd(&cnt[d4.x >> 8], 1);
    atomicAdd(&cnt[d4.y >> 8], 1);
    atomicAdd(&cnt[d4.z >> 8], 1);
    atomicAdd(&cnt[d4.w >> 8], 1);
  }
  __syncthreads();
  if (t < NBUCK && cnt[t]) atomicAdd(&bcnt[t], cnt[t]);
}

__global__ void k_bscan(const int* __restrict__ bcnt, int* __restrict__ bbase,
                        int* __restrict__ bcur, int* __restrict__ rowstart) {
  __shared__ int lds[256];
  int t = threadIdx.x;
  int v = (t < NBUCK) ? bcnt[t] : 0;
  lds[t] = v;
  __syncthreads();
  #pragma unroll
  for (int off = 1; off < 256; off <<= 1) {
    int tv = (t >= off) ? lds[t - off] : 0;
    __syncthreads();
    lds[t] += tv;
    __syncthreads();
  }
  int ex = lds[t] - v;
  if (t < NBUCK) { bbase[t] = ex; bcur[t] = ex; }
  if (t == NBUCK - 1) bbase[NBUCK] = ex + v;  // = N_EDGES
  if (t == 0) rowstart[N_NODES] = N_EDGES;
}

// pack: bits[15:0]=src, [18:16]=et, [31:24]=dst&255
__global__ void k_bucket(const int* __restrict__ src, const int* __restrict__ dst,
                         const int* __restrict__ et, int* __restrict__ bcur,
                         u32* __restrict__ tmp) {
  int i = blockIdx.x * 256 + threadIdx.x;
  if (i >= N_EDGES / 4) return;
  int4 s4 = ((const int4*)src)[i];
  int4 d4 = ((const int4*)dst)[i];
  int4 t4 = ((const int4*)et)[i];
  int p0 = atomicAdd(&bcur[d4.x >> 8], 1);
  int p1 = atomicAdd(&bcur[d4.y >> 8], 1);
  int p2 = atomicAdd(&bcur[d4.z >> 8], 1);
  int p3 = atomicAdd(&bcur[d4.w >> 8], 1);
  tmp[p0] = (u32)s4.x | ((u32)t4.x << 16) | ((u32)(d4.x & 255) << 24);
  tmp[p1] = (u32)s4.y | ((u32)t4.y << 16) | ((u32)(d4.y & 255) << 24);
  tmp[p2] = (u32)s4.z | ((u32)t4.z << 16) | ((u32)(d4.z & 255) << 24);
  tmp[p3] = (u32)s4.w | ((u32)t4.w << 16) | ((u32)(d4.w & 255) << 24);
}

// per bucket: LDS hist+scan of its edges -> rowstart + ordered epk (sequential
// writes into the bucket's contiguous region)
__global__ __launch_bounds__(256) void k_local(const u32* __restrict__ tmp,
                                               const int* __restrict__ bbase,
                                               int* __restrict__ rowstart,
                                               int* __restrict__ epk) {
  __shared__ int hist[256];
  __shared__ int excl[256];
  __shared__ int cur[256];
  const int b = blockIdx.x;
  const int t = threadIdx.x;
  const int base = bbase[b];
  const int end = bbase[b + 1];
  hist[t] = 0;
  cur[t] = 0;
  __syncthreads();
  for (int i = base + t; i < end; i += 256) atomicAdd(&hist[tmp[i] >> 24], 1);
  __syncthreads();
  int v = hist[t];
  excl[t] = v;
  __syncthreads();
  #pragma unroll
  for (int off = 1; off < 256; off <<= 1) {
    int tv = (t >= off) ? excl[t - off] : 0;
    __syncthreads();
    excl[t] += tv;
    __syncthreads();
  }
  int myexcl = excl[t] - v;
  excl[t] = myexcl;
  int n = b * 256 + t;
  if (n < N_NODES) rowstart[n] = base + myexcl;
  __syncthreads();
  for (int i = base + t; i < end; i += 256) {
    u32 p = tmp[i];
    int lo = p >> 24;
    int o = atomicAdd(&cur[lo], 1);
    epk[base + excl[lo] + o] = (int)(p & 0x7ffffu);  // (et<<16)|src
  }
}

// ---- hW = h @ W_r via MFMA + fused logit-table GEMM ------------------------
__global__ __launch_bounds__(256) void k_hw(const u16* __restrict__ hb,
                                            const u16* __restrict__ WbT,
                                            const u16* __restrict__ Tb,
                                            u16* __restrict__ hW,
                                            float* __restrict__ tbl) {
  const int wv = threadIdx.x >> 6;
  const int lane = threadIdx.x & 63;
  const int l15 = lane & 15;
  const int kg = lane >> 4;
  const int n = blockIdx.x * 64 + wv * 16 + l15;
  const bf16x8* hrow = (const bf16x8*)(hb + (size_t)n * DIM);
  const bf16x8 b0 = hrow[kg];
  const bf16x8 b1 = hrow[4 + kg];
  const bool ok = (n < N_NODES);
  {
    const bf16x8* trow = (const bf16x8*)(Tb + (size_t)l15 * DIM);
    f32x4 acc = {0.f, 0.f, 0.f, 0.f};
    acc = __builtin_amdgcn_mfma_f32_16x16x32_bf16(trow[kg], b0, acc, 0, 0, 0);
    acc = __builtin_amdgcn_mfma_f32_16x16x32_bf16(trow[4 + kg], b1, acc, 0, 0, 0);
    if (ok) *(f32x4*)(tbl + (size_t)n * 16 + kg * 4) = acc;
  }
  #pragma unroll
  for (int r = 0; r < NREL; ++r) {
    #pragma unroll
    for (int dt = 0; dt < 4; ++dt) {
      const int d = dt * 16 + l15;
      const bf16x8* wrow = (const bf16x8*)(WbT + ((size_t)r * DIM + d) * DIM);
      f32x4 acc = {0.f, 0.f, 0.f, 0.f};
      acc = __builtin_amdgcn_mfma_f32_16x16x32_bf16(wrow[kg], b0, acc, 0, 0, 0);
      acc = __builtin_amdgcn_mfma_f32_16x16x32_bf16(wrow[4 + kg], b1, acc, 0, 0, 0);
      if (ok) {
        uint2 s;
        s.x = (u32)f2b(acc[0]) | ((u32)f2b(acc[1]) << 16);
        s.y = (u32)f2b(acc[2]) | ((u32)f2b(acc[3]) << 16);
        *(uint2*)(hW + ((size_t)r * N_NODES + n) * DIM + dt * 16 + kg * 4) = s;
      }
    }
  }
}

// ---- fused softmax+reduce: wave/node, 16 edge slots x 4 lanes (32B each) ---
__global__ void k_fused(const float* __restrict__ h, const u16* __restrict__ hW,
                        const float* __restrict__ tbl,
                        const int* __restrict__ rowstart, const int* __restrict__ epk,
                        const float* __restrict__ dmask, float* __restrict__ out) {
  const int node = blockIdx.x * 4 + (threadIdx.x >> 6);
  const int lane = threadIdx.x & 63;
  const int g = lane >> 2;   // edge slot 0..15
  const int l = lane & 3;    // 32B quarter of the 128B row
  const int s = rowstart[node];
  const int e = rowstart[node + 1];
  float acc[16];
  #pragma unroll
  for (int i = 0; i < 16; ++i) acc[i] = 0.f;
  float den = 0.f;
  for (int j = s; j < e; j += 16) {
    const int idx = j + g;
    const bool valid = idx < e;
    const int p = valid ? epk[idx] : 0;
    const int sv = p & 0xffff;
    const int rv = (p >> 16) & 7;
    float lg = tbl[(size_t)node * 16 + rv] + tbl[(size_t)sv * 16 + 8 + rv];
    lg = lg > 0.f ? lg : 0.2f * lg;
    const float w = valid ? __expf(lg) : 0.f;
    den += w;
    uint4 q0 = {0u, 0u, 0u, 0u}, q1 = {0u, 0u, 0u, 0u};
    if (valid) {
      const u16* row = hW + ((size_t)rv * N_NODES + sv) * DIM + l * 16;
      q0 = *(const uint4*)row;
      q1 = *(const uint4*)(row + 8);
    }
    const u32 qa[8] = {q0.x, q0.y, q0.z, q0.w, q1.x, q1.y, q1.z, q1.w};
    #pragma unroll
    for (int c = 0; c < 8; ++c) {
      acc[2 * c]     += w * b2f((u16)(qa[c] & 0xffff));
      acc[2 * c + 1] += w * b2f((u16)(qa[c] >> 16));
    }
  }
  #pragma unroll
  for (int m = 4; m <= 32; m <<= 1) {
    den += __shfl_xor(den, m, 64);
    #pragma unroll
    for (int i = 0; i < 16; ++i) acc[i] += __shfl_xor(acc[i], m, 64);
  }
  if (lane < 4) {
    const float inv = 1.f / (den + 1e-9f);
    #pragma unroll
    for (int c = 0; c < 4; ++c) {
      const float4 hv = *(const float4*)(h + (size_t)node * DIM + l * 16 + c * 4);
      const float4 dm = *(const float4*)(dmask + l * 16 + c * 4);
      float4 o;
      o.x = hv.x + acc[c * 4 + 0] * inv * dm.x;
      o.y = hv.y + acc[c * 4 + 1] * inv * dm.y;
      o.z = hv.z + acc[c * 4 + 2] * inv * dm.z;
      o.w = hv.w + acc[c * 4 + 3] * inv * dm.w;
      *(float4*)(out + (size_t)node * DIM + l * 16 + c * 4) = o;
    }
  }
}

extern "C" void kernel_launch(void* const* d_in, const int* in_sizes, int n_in,
                              void* d_out, int out_size, void* d_ws, size_t ws_size,
                              hipStream_t stream) {
  const float* h = (const float*)d_in[0];
  const float* W = (const float*)d_in[1];
  const float* a = (const float*)d_in[2];
  const float* dmask = (const float*)d_in[3];
  const int* src = (const int*)d_in[4];
  const int* dst = (const int*)d_in[5];
  const int* et = (const int*)d_in[6];
  float* out = (float*)d_out;

  char* ws = (char*)d_ws;
  size_t off = 0;
  auto alloc = [&](size_t bytes) {
    void* p = ws + off;
    off += (bytes + 255) & ~(size_t)255;
    return p;
  };
  u16* hWbuf = (u16*)alloc((size_t)NREL * N_NODES * DIM * 2);  // 51.2 MB
  u16* hb = (u16*)alloc((size_t)NPAD * DIM * 2);               // 6.4 MB
  u16* WbT = (u16*)alloc((size_t)NREL * DIM * DIM * 2);
  u16* Tb = (u16*)alloc(16 * DIM * 2);
  float* tbl = (float*)alloc((size_t)N_NODES * 16 * 4);        // 3.2 MB
  float* Wa2 = (float*)alloc(NREL * DIM * 4);
  int* rowstart = (int*)alloc((N_NODES + 1) * 4);
  int* bcnt = (int*)alloc(NBUCK * 4);
  int* bbase = (int*)alloc((NBUCK + 1) * 4);
  int* bcur = (int*)alloc(NBUCK * 4);
  u32* tmp = (u32*)alloc((size_t)N_EDGES * 4);                 // 3.2 MB
  int* epk = (int*)alloc((size_t)N_EDGES * 4);                 // 3.2 MB
  (void)off; (void)ws_size;

  hipMemsetAsync(bcnt, 0, NBUCK * 4, stream);
  k_cast_h<<<(NPAD * DIM / 4 + 255) / 256, 256, 0, stream>>>(h, hb);
  k_cast_wt<<<NREL, 256, 0, stream>>>(W, a, WbT, Wa2);
  k_prep_tbl<<<1, 256, 0, stream>>>(a, Wa2, Tb);
  k_bhist<<<(N_EDGES / 4 + 255) / 256, 256, 0, stream>>>(dst, bcnt);
  k_bscan<<<1, 256, 0, stream>>>(bcnt, bbase, bcur, rowstart);
  k_bucket<<<(N_EDGES / 4 + 255) / 256, 256, 0, stream>>>(src, dst, et, bcur, tmp);
  k_local<<<NBUCK, 256, 0, stream>>>(tmp, bbase, rowstart, epk);
  k_hw<<<NBLK, 256, 0, stream>>>(hb, WbT, Tb, hWbuf, tbl);
  k_fused<<<N_NODES / 4, 256, 0, stream>>>(h, hWbuf, tbl, rowstart, epk, dmask, out);
}

// Round 5
// 120.856 us; speedup vs baseline: 4.8085x; 4.8085x over previous
//
#include <hip/hip_runtime.h>
#include <cstdint>
#include <cstddef>

#define N_NODES 50000
#define N_EDGES 800000
#define NE4 (N_EDGES / 4)        // 200000 int4 records
#define DIM 64
#define NREL 8
#define NBLK 782                 // ceil(N_NODES/64)
#define NPAD (NBLK * 64)         // 50048
#define NBUCK 196                // ceil(N_NODES/256): bucket = dst>>8
#define NCHUNK 196               // edge chunks of 4096
#define CHUNK4 1024              // int4 loads per chunk
#define NP (NBUCK * NCHUNK)      // 38416 count-matrix entries
#define NB1 151                  // ceil(NP/256)

typedef unsigned short u16;
typedef unsigned int u32;
typedef float f32x4 __attribute__((ext_vector_type(4)));
typedef short bf16x8 __attribute__((ext_vector_type(8)));

__device__ __forceinline__ u16 f2b(float f) {
  union { float f; u32 u; } c; c.f = f;
  u32 u = c.u;
  return (u16)((u + 0x7fffu + ((u >> 16) & 1u)) >> 16);  // RNE
}
__device__ __forceinline__ float b2f(u16 v) {
  union { u32 u; float f; } c; c.u = ((u32)v) << 16;
  return c.f;
}

// ---- casts -----------------------------------------------------------------
__global__ void k_cast_h(const float* __restrict__ h, u16* __restrict__ hb) {
  size_t i4 = (size_t)blockIdx.x * 256 + threadIdx.x;
  size_t base = i4 * 4;
  if (base >= (size_t)NPAD * DIM) return;
  size_t row = base >> 6;
  u16 o[4];
  if (row < N_NODES) {
    float4 v = *(const float4*)(h + base);
    o[0] = f2b(v.x); o[1] = f2b(v.y); o[2] = f2b(v.z); o[3] = f2b(v.w);
  } else {
    o[0] = o[1] = o[2] = o[3] = 0;
  }
  uint2 s; s.x = (u32)o[0] | ((u32)o[1] << 16); s.y = (u32)o[2] | ((u32)o[3] << 16);
  *(uint2*)(hb + base) = s;
}

// block r: WbT[r][d][k] = W[r][k][d] (bf16); Tb row r = a[r,:D], row 8+r = Wa2[r]
__global__ void k_cast_wt(const float* __restrict__ W, const float* __restrict__ a,
                          u16* __restrict__ WbT, u16* __restrict__ Tb) {
  int r = blockIdx.x;
  for (int idx = threadIdx.x; idx < DIM * DIM; idx += 256) {
    int d = idx >> 6, k = idx & 63;
    WbT[((size_t)r * DIM + d) * DIM + k] = f2b(W[((size_t)r * DIM + k) * DIM + d]);
  }
  if (threadIdx.x < DIM) {
    int d = threadIdx.x;
    const float* Wr = W + (size_t)r * DIM * DIM + (size_t)d * DIM;
    const float* ar = a + (size_t)r * 2 * DIM + DIM;
    float acc = 0.f;
    #pragma unroll
    for (int e = 0; e < DIM; ++e) acc += Wr[e] * ar[e];
    Tb[(8 + r) * DIM + d] = f2b(acc);          // src-side: Wa2[r]
    Tb[r * DIM + d] = f2b(a[r * 2 * DIM + d]); // dst-side: a[r,:D]
  }
}

// ---- deterministic two-pass bucket partition -------------------------------
// pass 1: per-chunk LDS histogram -> pcnt[bucket][chunk]
__global__ __launch_bounds__(256) void k_pcount(const int* __restrict__ dst,
                                                int* __restrict__ pcnt) {
  __shared__ int cnt[256];
  const int t = threadIdx.x, c = blockIdx.x;
  cnt[t] = 0;
  __syncthreads();
  const int base4 = c * CHUNK4;
  const int end4 = (base4 + CHUNK4 < NE4) ? base4 + CHUNK4 : NE4;
  for (int i = base4 + t; i < end4; i += 256) {
    int4 d4 = ((const int4*)dst)[i];
    atomicAdd(&cnt[d4.x >> 8], 1);
    atomicAdd(&cnt[d4.y >> 8], 1);
    atomicAdd(&cnt[d4.z >> 8], 1);
    atomicAdd(&cnt[d4.w >> 8], 1);
  }
  __syncthreads();
  if (t < NBUCK) pcnt[t * NCHUNK + c] = cnt[t];
}

// generic 3-kernel exclusive scan over NP entries (row-major = bucket-major)
__global__ void k_scanA(const int* __restrict__ in, int* __restrict__ out,
                        int* __restrict__ bsum) {
  __shared__ int lds[256];
  int t = threadIdx.x;
  int i = blockIdx.x * 256 + t;
  int v = (i < NP) ? in[i] : 0;
  lds[t] = v;
  __syncthreads();
  #pragma unroll
  for (int off = 1; off < 256; off <<= 1) {
    int tv = (t >= off) ? lds[t - off] : 0;
    __syncthreads();
    lds[t] += tv;
    __syncthreads();
  }
  if (i < NP) out[i] = lds[t] - v;
  if (t == 255) bsum[blockIdx.x] = lds[255];
}

__global__ void k_scanB(const int* __restrict__ bsum, int* __restrict__ boff,
                        int* __restrict__ bbase, int* __restrict__ rowstart) {
  __shared__ int lds[256];
  int t = threadIdx.x;
  int v = (t < NB1) ? bsum[t] : 0;
  lds[t] = v;
  __syncthreads();
  #pragma unroll
  for (int off = 1; off < 256; off <<= 1) {
    int tv = (t >= off) ? lds[t - off] : 0;
    __syncthreads();
    lds[t] += tv;
    __syncthreads();
  }
  if (t < NB1) boff[t] = lds[t] - v;
  if (t == 0) { bbase[NBUCK] = N_EDGES; rowstart[N_NODES] = N_EDGES; }
}

__global__ void k_scanC(int* __restrict__ gbase, const int* __restrict__ boff,
                        int* __restrict__ bbase) {
  int i = blockIdx.x * 256 + threadIdx.x;
  if (i >= NP) return;
  int v = gbase[i] + boff[blockIdx.x];
  gbase[i] = v;
  if (i % NCHUNK == 0) bbase[i / NCHUNK] = v;
}

// pass 2: re-read edges, LDS cursors seeded from gbase, sequential-stream writes
// pack: bits[15:0]=src, [18:16]=et, [31:24]=dst&255
__global__ __launch_bounds__(256) void k_ppart(const int* __restrict__ src,
                                               const int* __restrict__ dst,
                                               const int* __restrict__ et,
                                               const int* __restrict__ gbase,
                                               u32* __restrict__ tmp) {
  __shared__ int cur[256];
  const int t = threadIdx.x, c = blockIdx.x;
  if (t < NBUCK) cur[t] = gbase[t * NCHUNK + c];
  __syncthreads();
  const int base4 = c * CHUNK4;
  const int end4 = (base4 + CHUNK4 < NE4) ? base4 + CHUNK4 : NE4;
  for (int i = base4 + t; i < end4; i += 256) {
    int4 s4 = ((const int4*)src)[i];
    int4 d4 = ((const int4*)dst)[i];
    int4 t4 = ((const int4*)et)[i];
    int p0 = atomicAdd(&cur[d4.x >> 8], 1);
    int p1 = atomicAdd(&cur[d4.y >> 8], 1);
    int p2 = atomicAdd(&cur[d4.z >> 8], 1);
    int p3 = atomicAdd(&cur[d4.w >> 8], 1);
    tmp[p0] = (u32)s4.x | ((u32)t4.x << 16) | ((u32)(d4.x & 255) << 24);
    tmp[p1] = (u32)s4.y | ((u32)t4.y << 16) | ((u32)(d4.y & 255) << 24);
    tmp[p2] = (u32)s4.z | ((u32)t4.z << 16) | ((u32)(d4.z & 255) << 24);
    tmp[p3] = (u32)s4.w | ((u32)t4.w << 16) | ((u32)(d4.w & 255) << 24);
  }
}

// per bucket: LDS hist+scan -> rowstart + node-ordered epk (sequential writes)
__global__ __launch_bounds__(256) void k_local(const u32* __restrict__ tmp,
                                               const int* __restrict__ bbase,
                                               int* __restrict__ rowstart,
                                               int* __restrict__ epk) {
  __shared__ int hist[256];
  __shared__ int excl[256];
  __shared__ int cur[256];
  const int b = blockIdx.x;
  const int t = threadIdx.x;
  const int base = bbase[b];
  const int end = bbase[b + 1];
  hist[t] = 0;
  cur[t] = 0;
  __syncthreads();
  for (int i = base + t; i < end; i += 256) atomicAdd(&hist[tmp[i] >> 24], 1);
  __syncthreads();
  int v = hist[t];
  excl[t] = v;
  __syncthreads();
  #pragma unroll
  for (int off = 1; off < 256; off <<= 1) {
    int tv = (t >= off) ? excl[t - off] : 0;
    __syncthreads();
    excl[t] += tv;
    __syncthreads();
  }
  int myexcl = excl[t] - v;
  excl[t] = myexcl;
  int n = b * 256 + t;
  if (n < N_NODES) rowstart[n] = base + myexcl;
  __syncthreads();
  for (int i = base + t; i < end; i += 256) {
    u32 p = tmp[i];
    int lo = p >> 24;
    int o = atomicAdd(&cur[lo], 1);
    epk[base + excl[lo] + o] = (int)(p & 0x7ffffu);  // (et<<16)|src
  }
}

// ---- hW = h @ W_r via MFMA + fused logit-table GEMM ------------------------
__global__ __launch_bounds__(256) void k_hw(const u16* __restrict__ hb,
                                            const u16* __restrict__ WbT,
                                            const u16* __restrict__ Tb,
                                            u16* __restrict__ hW,
                                            float* __restrict__ tbl) {
  const int wv = threadIdx.x >> 6;
  const int lane = threadIdx.x & 63;
  const int l15 = lane & 15;
  const int kg = lane >> 4;
  const int n = blockIdx.x * 64 + wv * 16 + l15;
  const bf16x8* hrow = (const bf16x8*)(hb + (size_t)n * DIM);
  const bf16x8 b0 = hrow[kg];
  const bf16x8 b1 = hrow[4 + kg];
  const bool ok = (n < N_NODES);
  {
    const bf16x8* trow = (const bf16x8*)(Tb + (size_t)l15 * DIM);
    f32x4 acc = {0.f, 0.f, 0.f, 0.f};
    acc = __builtin_amdgcn_mfma_f32_16x16x32_bf16(trow[kg], b0, acc, 0, 0, 0);
    acc = __builtin_amdgcn_mfma_f32_16x16x32_bf16(trow[4 + kg], b1, acc, 0, 0, 0);
    if (ok) *(f32x4*)(tbl + (size_t)n * 16 + kg * 4) = acc;
  }
  #pragma unroll
  for (int r = 0; r < NREL; ++r) {
    #pragma unroll
    for (int dt = 0; dt < 4; ++dt) {
      const int d = dt * 16 + l15;
      const bf16x8* wrow = (const bf16x8*)(WbT + ((size_t)r * DIM + d) * DIM);
      f32x4 acc = {0.f, 0.f, 0.f, 0.f};
      acc = __builtin_amdgcn_mfma_f32_16x16x32_bf16(wrow[kg], b0, acc, 0, 0, 0);
      acc = __builtin_amdgcn_mfma_f32_16x16x32_bf16(wrow[4 + kg], b1, acc, 0, 0, 0);
      if (ok) {
        uint2 s;
        s.x = (u32)f2b(acc[0]) | ((u32)f2b(acc[1]) << 16);
        s.y = (u32)f2b(acc[2]) | ((u32)f2b(acc[3]) << 16);
        *(uint2*)(hW + ((size_t)r * N_NODES + n) * DIM + dt * 16 + kg * 4) = s;
      }
    }
  }
}

// ---- fused softmax+reduce: wave/node, 16 edge slots x 4 lanes (32B each) ---
__global__ void k_fused(const float* __restrict__ h, const u16* __restrict__ hW,
                        const float* __restrict__ tbl,
                        const int* __restrict__ rowstart, const int* __restrict__ epk,
                        const float* __restrict__ dmask, float* __restrict__ out) {
  const int node = blockIdx.x * 4 + (threadIdx.x >> 6);
  const int lane = threadIdx.x & 63;
  const int g = lane >> 2;   // edge slot 0..15
  const int l = lane & 3;    // 32B quarter of the 128B row
  const int s = rowstart[node];
  const int e = rowstart[node + 1];
  float acc[16];
  #pragma unroll
  for (int i = 0; i < 16; ++i) acc[i] = 0.f;
  float den = 0.f;
  for (int j = s; j < e; j += 16) {
    const int idx = j + g;
    const bool valid = idx < e;
    const int p = valid ? epk[idx] : 0;
    const int sv = p & 0xffff;
    const int rv = (p >> 16) & 7;
    float lg = tbl[(size_t)node * 16 + rv] + tbl[(size_t)sv * 16 + 8 + rv];
    lg = lg > 0.f ? lg : 0.2f * lg;
    const float w = valid ? __expf(lg) : 0.f;
    den += w;
    uint4 q0 = {0u, 0u, 0u, 0u}, q1 = {0u, 0u, 0u, 0u};
    if (valid) {
      const u16* row = hW + ((size_t)rv * N_NODES + sv) * DIM + l * 16;
      q0 = *(const uint4*)row;
      q1 = *(const uint4*)(row + 8);
    }
    const u32 qa[8] = {q0.x, q0.y, q0.z, q0.w, q1.x, q1.y, q1.z, q1.w};
    #pragma unroll
    for (int c = 0; c < 8; ++c) {
      acc[2 * c]     += w * b2f((u16)(qa[c] & 0xffff));
      acc[2 * c + 1] += w * b2f((u16)(qa[c] >> 16));
    }
  }
  #pragma unroll
  for (int m = 4; m <= 32; m <<= 1) {
    den += __shfl_xor(den, m, 64);
    #pragma unroll
    for (int i = 0; i < 16; ++i) acc[i] += __shfl_xor(acc[i], m, 64);
  }
  if (lane < 4) {
    const float inv = 1.f / (den + 1e-9f);
    #pragma unroll
    for (int c = 0; c < 4; ++c) {
      const float4 hv = *(const float4*)(h + (size_t)node * DIM + l * 16 + c * 4);
      const float4 dm = *(const float4*)(dmask + l * 16 + c * 4);
      float4 o;
      o.x = hv.x + acc[c * 4 + 0] * inv * dm.x;
      o.y = hv.y + acc[c * 4 + 1] * inv * dm.y;
      o.z = hv.z + acc[c * 4 + 2] * inv * dm.z;
      o.w = hv.w + acc[c * 4 + 3] * inv * dm.w;
      *(float4*)(out + (size_t)node * DIM + l * 16 + c * 4) = o;
    }
  }
}

extern "C" void kernel_launch(void* const* d_in, const int* in_sizes, int n_in,
                              void* d_out, int out_size, void* d_ws, size_t ws_size,
                              hipStream_t stream) {
  const float* h = (const float*)d_in[0];
  const float* W = (const float*)d_in[1];
  const float* a = (const float*)d_in[2];
  const float* dmask = (const float*)d_in[3];
  const int* src = (const int*)d_in[4];
  const int* dst = (const int*)d_in[5];
  const int* et = (const int*)d_in[6];
  float* out = (float*)d_out;

  char* ws = (char*)d_ws;
  size_t off = 0;
  auto alloc = [&](size_t bytes) {
    void* p = ws + off;
    off += (bytes + 255) & ~(size_t)255;
    return p;
  };
  u16* hWbuf = (u16*)alloc((size_t)NREL * N_NODES * DIM * 2);  // 51.2 MB
  u16* hb = (u16*)alloc((size_t)NPAD * DIM * 2);               // 6.4 MB
  u16* WbT = (u16*)alloc((size_t)NREL * DIM * DIM * 2);
  u16* Tb = (u16*)alloc(16 * DIM * 2);
  float* tbl = (float*)alloc((size_t)N_NODES * 16 * 4);        // 3.2 MB
  int* rowstart = (int*)alloc((N_NODES + 1) * 4);
  int* pcnt = (int*)alloc(NP * 4);
  int* gbase = (int*)alloc(NP * 4);
  int* bsum = (int*)alloc(NB1 * 4);
  int* boff = (int*)alloc(NB1 * 4);
  int* bbase = (int*)alloc((NBUCK + 1) * 4);
  u32* tmp = (u32*)alloc((size_t)N_EDGES * 4);                 // 3.2 MB
  int* epk = (int*)alloc((size_t)N_EDGES * 4);                 // 3.2 MB
  (void)off; (void)ws_size;

  k_cast_h<<<(NPAD * DIM / 4 + 255) / 256, 256, 0, stream>>>(h, hb);
  k_cast_wt<<<NREL, 256, 0, stream>>>(W, a, WbT, Tb);
  k_pcount<<<NCHUNK, 256, 0, stream>>>(dst, pcnt);
  k_scanA<<<NB1, 256, 0, stream>>>(pcnt, gbase, bsum);
  k_scanB<<<1, 256, 0, stream>>>(bsum, boff, bbase, rowstart);
  k_scanC<<<NB1, 256, 0, stream>>>(gbase, boff, bbase);
  k_ppart<<<NCHUNK, 256, 0, stream>>>(src, dst, et, gbase, tmp);
  k_local<<<NBUCK, 256, 0, stream>>>(tmp, bbase, rowstart, epk);
  k_hw<<<NBLK, 256, 0, stream>>>(hb, WbT, Tb, hWbuf, tbl);
  k_fused<<<N_NODES / 4, 256, 0, stream>>>(h, hWbuf, tbl, rowstart, epk, dmask, out);
}